// Round 9
// baseline (321.567 us; speedup 1.0000x reference)
//
#include <hip/hip_runtime.h>
#include <hip/hip_fp16.h>
#include <float.h>

#define NSEG 4096
#define CAP 2048   // max edges/segment held in LDS (max segment count ~330)

typedef __attribute__((ext_vector_type(8))) _Float16 half8;
typedef __attribute__((ext_vector_type(2))) _Float16 h2v;
typedef __attribute__((ext_vector_type(4))) float f32x4;

// ---- fused setup: seg_bounds (blocks 0..16) + pack_w (blocks 17..48) ----
__global__ __launch_bounds__(256) void setup(
    const int* __restrict__ batch, int* __restrict__ segs, int E,
    const float* __restrict__ Wj, const float* __restrict__ Wi,
    __half* __restrict__ Wpk) {
  const int bid = blockIdx.x;
  if (bid < 17) {
    // segment boundaries: segs[b] = first edge index with batch >= b
    int b = bid * 256 + threadIdx.x;
    if (b > NSEG) return;
    int lo = 0, hi = E;
    while (lo < hi) { int mid = (lo + hi) >> 1; if (batch[mid] < b) lo = mid + 1; else hi = mid; }
    segs[b] = lo;
  } else {
    // pack W_j / W_i into MFMA fragment order, split fp16 hi/lo.
    // Layout (halves): Wpk[which][kt*8+nt][h(0=hi,1=lo)][lane][r]
    //   value = W[k][n], k = kt*32 + (l>>4)*8 + r, n = nt*16 + (l&15)
    int tid = (bid - 17) * 256 + threadIdx.x;
    for (int idx = tid; idx < 2 * 4 * 8 * 64 * 8; idx += 32 * 256) {
      int r     = idx & 7;
      int l     = (idx >> 3) & 63;
      int nt    = (idx >> 9) & 7;
      int kt    = (idx >> 12) & 3;
      int which = idx >> 14;
      const float* W = which ? Wi : Wj;
      int k = kt * 32 + (l >> 4) * 8 + r;
      int n = nt * 16 + (l & 15);
      float v = W[k * 128 + n];
      __half hi = __float2half(v);                         // RNE
      __half lo = __float2half(v - __half2float(hi));      // exact residual
      size_t base = ((size_t)which * 32 + (size_t)(kt * 8 + nt)) * 1024;
      Wpk[base + l * 8 + r]       = hi;
      Wpk[base + 512 + l * 8 + r] = lo;
    }
  }
}

// ---- projection GEMM on matrix cores: Y = fp16(X @ W (+bias for which==1)) ----
// v5 PERSISTENT blocks (attack: v4 paid W-stage prologue + 4 barriers per
// 64-row block, 3126x; barrier coupling kept it ~2x off the 24us HBM floor):
//  - full 64 KB packed W (hi+lo) staged ONCE per block, ONE barrier, then
//    grid-stride over row-tiles with ZERO further syncs (W read-only, X
//    wave-private) -> waves free-run on the HBM X stream
//  - 512 thr (8 waves, 128 rows/tile), grid 256/matrix = exactly 2 blocks/CU
//    (128 KB LDS) -> 16 waves/CU, no barrier coupling
//  - full next-tile X prefetch (8 float4/lane ~ 1200cy cover vs ~900cy HBM)
//  - per-output MFMA order unchanged -> bitwise-identical Y
__global__ __launch_bounds__(512) void proj_mfma(
    const float* __restrict__ Xj, const float* __restrict__ Xi,
    const float* __restrict__ bias, const __half* __restrict__ Wpk,
    __half* __restrict__ Yj, __half* __restrict__ Yi, int nrows) {
  const int which = blockIdx.y;
  const float* X = which ? Xi : Xj;
  __half* Y = which ? Yi : Yj;

  __shared__ _Float16 Wlds[32768];   // 64 KB: [kt*8+nt][hi/lo][512 halves]

  const int tid  = threadIdx.x;
  const int wid  = tid >> 6;    // 8 waves
  const int lane = tid & 63;
  const int lr   = lane & 15;   // X row within the wave's 16-row tile
  const int lg   = lane >> 4;   // k-chunk group; D reg-quad selects output cols

  // ---- stage full packed W once: 4096 float4 / 512 thr = 8 each ----
  {
    const float4* src = (const float4*)(Wpk + (size_t)which * 32768);
    float4* dst = (float4*)Wlds;
    #pragma unroll
    for (int it = 0; it < 8; ++it)
      dst[it * 512 + tid] = src[it * 512 + tid];
  }

  const int ntiles = (nrows + 127) >> 7;   // 128 rows per tile
  const int NB = gridDim.x;

  // prefetch X for the first tile (overlaps the staging barrier)
  int tile = blockIdx.x;
  float4 cur[8], nxt[8];
  if (tile < ntiles) {
    long r = (long)tile * 128 + wid * 16 + lr;
    const float* p = X + (r < nrows ? r : 0) * 128 + lg * 8;
    #pragma unroll
    for (int kt = 0; kt < 4; ++kt) {
      cur[2 * kt]     = *(const float4*)(p + kt * 32);
      cur[2 * kt + 1] = *(const float4*)(p + kt * 32 + 4);
    }
  }

  __syncthreads();

#define CVT1(dsth, dstl, idx, val)                                   \
  { float v_ = (val); _Float16 h_ = (_Float16)v_;                    \
    dsth[idx] = h_; dstl[idx] = (_Float16)(v_ - (float)h_); }
#define CVT8(dsth, dstl, v0, v1)                                     \
  CVT1(dsth, dstl, 0, (v0).x) CVT1(dsth, dstl, 1, (v0).y)            \
  CVT1(dsth, dstl, 2, (v0).z) CVT1(dsth, dstl, 3, (v0).w)            \
  CVT1(dsth, dstl, 4, (v1).x) CVT1(dsth, dstl, 5, (v1).y)            \
  CVT1(dsth, dstl, 6, (v1).z) CVT1(dsth, dstl, 7, (v1).w)

#define MFMA(a, b, c) __builtin_amdgcn_mfma_f32_16x16x32_f16((a), (b), (c), 0, 0, 0)

  while (tile < ntiles) {
    const int tnext = tile + NB;
    if (tnext < ntiles) {
      long r = (long)tnext * 128 + wid * 16 + lr;
      const float* p = X + (r < nrows ? r : 0) * 128 + lg * 8;
      #pragma unroll
      for (int kt = 0; kt < 4; ++kt) {
        nxt[2 * kt]     = *(const float4*)(p + kt * 32);
        nxt[2 * kt + 1] = *(const float4*)(p + kt * 32 + 4);
      }
    }

    f32x4 acc[8] = {};
    #pragma unroll
    for (int kt = 0; kt < 4; ++kt) {
      half8 xh, xl;
      CVT8(xh, xl, cur[2 * kt], cur[2 * kt + 1]);
      #pragma unroll
      for (int nt = 0; nt < 8; ++nt) {
        const _Float16* f = &Wlds[(kt * 8 + nt) * 1024 + lane * 8];
        half8 wh = *(const half8*)(f);
        half8 wl = *(const half8*)(f + 512);
        acc[nt] = MFMA(wh, xh, acc[nt]);
        acc[nt] = MFMA(wh, xl, acc[nt]);
        acc[nt] = MFMA(wl, xh, acc[nt]);
      }
    }

    // epilogue: D (swapped operands): lane -> row = tile*128 + wid*16 + lr,
    // cols = nt*16 + lg*4 + (0..3) -> packed 8B stores
    long row = (long)tile * 128 + wid * 16 + lr;
    if (row < nrows) {
      __half* yr = Y + row * 128;
      #pragma unroll
      for (int nt = 0; nt < 8; ++nt) {
        float4 bv = make_float4(0.f, 0.f, 0.f, 0.f);
        if (which) bv = *(const float4*)(bias + nt * 16 + lg * 4);
        __half2 v01 = __floats2half2_rn(acc[nt][0] + bv.x, acc[nt][1] + bv.y);
        __half2 v23 = __floats2half2_rn(acc[nt][2] + bv.z, acc[nt][3] + bv.w);
        uint2 u;
        u.x = *(unsigned int*)&v01;
        u.y = *(unsigned int*)&v23;
        *(uint2*)(yr + nt * 16 + lg * 4) = u;
      }
    }

    #pragma unroll
    for (int i = 0; i < 8; ++i) cur[i] = nxt[i];
    tile = tnext;
  }

#undef MFMA
#undef CVT8
#undef CVT1
}

// One block per segment. (FROZEN since R7 — at a pattern-BW wall: 72-76 us /
// 3.3-3.4 TB/s beyond-L2 invariant across 4 structures; traffic irreducible
// in fp16 and fp8 fails the error budget)
__global__ __launch_bounds__(256) void seg_softmax(
    const __half* __restrict__ xjp, const __half* __restrict__ xip,
    const int* __restrict__ ei, const int* __restrict__ segs,
    const float* __restrict__ mlpW, const float* __restrict__ prelu_w,
    const float* __restrict__ mlp_b, float* __restrict__ out, int E) {
  const int start = segs[blockIdx.x];
  const int end = segs[blockIdx.x + 1];
  const int cnt = end - start;
  if (cnt <= 0) return;

  __shared__ float aS[CAP];
  __shared__ float red[8];

  const int tid = threadIdx.x;
  const int lane = tid & 63;
  const int wid = tid >> 6;
  const int g   = tid >> 4;          // 16 quarter-wave groups per block
  const int ql  = tid & 15;          // lane within group: 8 features x fp16

  const float4 w0 = *(const float4*)(mlpW + ql * 8);
  const float4 w1 = *(const float4*)(mlpW + ql * 8 + 4);
  const float pw = prelu_w[0];
  const float mb = mlp_b[0];
  const bool useLds = (cnt <= CAP);

  const uint4* XJ = (const uint4*)xjp;   // one row = 16 uint4 (256 B)
  const uint4* XI = (const uint4*)xip;
  const h2v pwv = { (_Float16)pw, (_Float16)pw };
  const h2v zv  = { (_Float16)0.f, (_Float16)0.f };

  // ---- phase 1: alpha (4 consecutive edges per group per iteration) ----
  for (int e0 = start + g * 4; e0 < end; e0 += 64) {
    const int eB = e0 + 1, eC = e0 + 2, eD = e0 + 3;
    const bool vB = (eB < end), vC = (eC < end), vD = (eD < end);
    int sA = ei[e0],            dA = ei[E + e0];
    int sB = vB ? ei[eB] : sA,  dB = vB ? ei[E + eB] : dA;
    int sC = vC ? ei[eC] : sA,  dC = vC ? ei[E + eC] : dA;
    int sD = vD ? ei[eD] : sA,  dD = vD ? ei[E + eD] : dA;

    uint4 aA = XJ[(size_t)sA * 16 + ql], bA = XI[(size_t)dA * 16 + ql];
    uint4 aB = XJ[(size_t)sB * 16 + ql], bB = XI[(size_t)dB * 16 + ql];
    uint4 aC = XJ[(size_t)sC * 16 + ql], bC = XI[(size_t)dC * 16 + ql];
    uint4 aD = XJ[(size_t)sD * 16 + ql], bD = XI[(size_t)dD * 16 + ql];

    float pA, pB, pC, pD;
#define EALPHA(av, bv, p)                                                   \
    {                                                                       \
      h2v h0 = *(h2v*)&(av).x + *(h2v*)&(bv).x;                             \
      h2v h1 = *(h2v*)&(av).y + *(h2v*)&(bv).y;                             \
      h2v h2 = *(h2v*)&(av).z + *(h2v*)&(bv).z;                             \
      h2v h3 = *(h2v*)&(av).w + *(h2v*)&(bv).w;                             \
      h0 = __builtin_elementwise_max(h0, zv)                                \
         + pwv * __builtin_elementwise_min(h0, zv);                         \
      h1 = __builtin_elementwise_max(h1, zv)                                \
         + pwv * __builtin_elementwise_min(h1, zv);                         \
      h2 = __builtin_elementwise_max(h2, zv)                                \
         + pwv * __builtin_elementwise_min(h2, zv);                         \
      h3 = __builtin_elementwise_max(h3, zv)                                \
         + pwv * __builtin_elementwise_min(h3, zv);                         \
      p = (float)h0.x * w0.x;                                               \
      p = fmaf((float)h0.y, w0.y, p); p = fmaf((float)h1.x, w0.z, p);       \
      p = fmaf((float)h1.y, w0.w, p); p = fmaf((float)h2.x, w1.x, p);       \
      p = fmaf((float)h2.y, w1.y, p); p = fmaf((float)h3.x, w1.z, p);       \
      p = fmaf((float)h3.y, w1.w, p);                                       \
    }
    EALPHA(aA, bA, pA);
    EALPHA(aB, bB, pB);
    EALPHA(aC, bC, pC);
    EALPHA(aD, bD, pD);
#undef EALPHA

    #pragma unroll
    for (int off = 1; off < 16; off <<= 1) {
      pA += __shfl_xor(pA, off, 64);
      pB += __shfl_xor(pB, off, 64);
      pC += __shfl_xor(pC, off, 64);
      pD += __shfl_xor(pD, off, 64);
    }
    if (ql == 0) {
      if (useLds) {
        aS[e0 - start] = pA + mb;
        if (vB) aS[eB - start] = pB + mb;
        if (vC) aS[eC - start] = pC + mb;
        if (vD) aS[eD - start] = pD + mb;
      } else {
        out[e0] = pA + mb;
        if (vB) out[eB] = pB + mb;
        if (vC) out[eC] = pC + mb;
        if (vD) out[eD] = pD + mb;
      }
    }
  }
  __syncthreads();

  // ---- phase 2: block max ----
  float m = -FLT_MAX;
  if (useLds) { for (int i = tid; i < cnt; i += 256) m = fmaxf(m, aS[i]); }
  else        { for (int i = tid; i < cnt; i += 256) m = fmaxf(m, out[start + i]); }
  #pragma unroll
  for (int off = 1; off < 64; off <<= 1) m = fmaxf(m, __shfl_xor(m, off, 64));
  if (lane == 0) red[wid] = m;
  __syncthreads();
  m = fmaxf(fmaxf(red[0], red[1]), fmaxf(red[2], red[3]));

  // ---- phase 3: exp + block sum ----
  float s = 0.f;
  if (useLds) {
    for (int i = tid; i < cnt; i += 256) { float x = expf(aS[i] - m); aS[i] = x; s += x; }
  } else {
    for (int i = tid; i < cnt; i += 256) { float x = expf(out[start + i] - m); out[start + i] = x; s += x; }
  }
  #pragma unroll
  for (int off = 1; off < 64; off <<= 1) s += __shfl_xor(s, off, 64);
  if (lane == 0) red[4 + wid] = s;
  __syncthreads();
  s = (red[4] + red[5]) + (red[6] + red[7]);

  // ---- phase 4: normalize + write ----
  const float inv = 1.0f / (s + 1e-16f);
  if (useLds) { for (int i = tid; i < cnt; i += 256) out[start + i] = aS[i] * inv; }
  else        { for (int i = tid; i < cnt; i += 256) out[start + i] *= inv; }
}

extern "C" void kernel_launch(void* const* d_in, const int* in_sizes, int n_in,
                              void* d_out, int out_size, void* d_ws, size_t ws_size,
                              hipStream_t stream) {
  const float* x_j      = (const float*)d_in[0];
  const float* x_i      = (const float*)d_in[1];
  const int*   edge_idx = (const int*)d_in[2];
  const int*   batch    = (const int*)d_in[3];
  const float* w_j      = (const float*)d_in[4];
  const float* w_i      = (const float*)d_in[5];
  const float* bias     = (const float*)d_in[6];
  const float* prelu_w  = (const float*)d_in[7];
  const float* mlp_W    = (const float*)d_in[8];
  const float* mlp_b    = (const float*)d_in[9];
  const int nnodes = in_sizes[0] / 128;
  const int E = in_sizes[3];

  __half* Wpk = (__half*)d_ws;                    // 65536 halves = 128 KB
  __half* xjp = Wpk + 65536;
  __half* xip = xjp + (size_t)nnodes * 128;
  int* segs   = (int*)(xip + (size_t)nnodes * 128);

  hipLaunchKernelGGL(setup, dim3(49), dim3(256), 0, stream,
                     batch, segs, E, w_j, w_i, Wpk);

  // persistent: 256 blocks per matrix x 512 thr = exactly 2 blocks/CU
  hipLaunchKernelGGL(proj_mfma, dim3(256, 2), dim3(512), 0, stream,
                     x_j, x_i, bias, Wpk, xjp, xip, nnodes);

  hipLaunchKernelGGL(seg_softmax, dim3(NSEG), dim3(256), 0, stream,
                     xjp, xip, edge_idx, segs, mlp_W, prelu_w, mlp_b,
                     (float*)d_out, E);
}

// Round 10
// 244.973 us; speedup vs baseline: 1.3127x; 1.3127x over previous
//
#include <hip/hip_runtime.h>
#include <hip/hip_fp16.h>
#include <float.h>

#define NSEG 4096
#define CAP 2048   // max edges/segment held in LDS (max segment count ~330)

typedef __attribute__((ext_vector_type(8))) _Float16 half8;
typedef __attribute__((ext_vector_type(2))) _Float16 h2v;
typedef __attribute__((ext_vector_type(4))) float f32x4;

// ---- fused setup: seg_bounds (blocks 0..16) + pack_w (blocks 17..48) ----
__global__ __launch_bounds__(256) void setup(
    const int* __restrict__ batch, int* __restrict__ segs, int E,
    const float* __restrict__ Wj, const float* __restrict__ Wi,
    __half* __restrict__ Wpk) {
  const int bid = blockIdx.x;
  if (bid < 17) {
    // segment boundaries: segs[b] = first edge index with batch >= b
    int b = bid * 256 + threadIdx.x;
    if (b > NSEG) return;
    int lo = 0, hi = E;
    while (lo < hi) { int mid = (lo + hi) >> 1; if (batch[mid] < b) lo = mid + 1; else hi = mid; }
    segs[b] = lo;
  } else {
    // pack W_j / W_i into MFMA fragment order, split fp16 hi/lo.
    // Layout (halves): Wpk[which][kt*8+nt][h(0=hi,1=lo)][lane][r]
    //   value = W[k][n], k = kt*32 + (l>>4)*8 + r, n = nt*16 + (l&15)
    int tid = (bid - 17) * 256 + threadIdx.x;
    for (int idx = tid; idx < 2 * 4 * 8 * 64 * 8; idx += 32 * 256) {
      int r     = idx & 7;
      int l     = (idx >> 3) & 63;
      int nt    = (idx >> 9) & 7;
      int kt    = (idx >> 12) & 3;
      int which = idx >> 14;
      const float* W = which ? Wi : Wj;
      int k = kt * 32 + (l >> 4) * 8 + r;
      int n = nt * 16 + (l & 15);
      float v = W[k * 128 + n];
      __half hi = __float2half(v);                         // RNE
      __half lo = __float2half(v - __half2float(hi));      // exact residual
      size_t base = ((size_t)which * 32 + (size_t)(kt * 8 + nt)) * 1024;
      Wpk[base + l * 8 + r]       = hi;
      Wpk[base + 512 + l * 8 + r] = lo;
    }
  }
}

// ---- projection GEMM on matrix cores: Y = fp16(X @ W (+bias for which==1)) ----
// v4 (REVERTED from R9's persistent v5: strided persistent schedule destroyed
// L3/L2 locality — FETCH 103->212 MB, WRITE 51->158 MB (partial-line RMW
// amplification), proj 60->139 us. Dispatch-order locality > barrier savings.)
//  - 64-row blocks, dispatch-ordered; W staged in per-kt 16 KB chunks,
//    double-buffered in 32 KB LDS; write-late staging; X prefetch depth 2
//  - __launch_bounds__(256, 4): pin VGPR <=128 to guarantee 4 blocks/CU
//  - numerics bitwise-identical (split-fp16 3-MFMA, fixed accumulation order)
__global__ __launch_bounds__(256, 4) void proj_mfma(
    const float* __restrict__ Xj, const float* __restrict__ Xi,
    const float* __restrict__ bias, const __half* __restrict__ Wpk,
    __half* __restrict__ Yj, __half* __restrict__ Yi, int nrows) {
  const int which = blockIdx.y;
  const float* X = which ? Xi : Xj;
  __half* Y = which ? Yi : Yj;
  const _Float16* WpkB = (const _Float16*)Wpk + (size_t)which * 32768;

  __shared__ _Float16 Wlds[2][8192];   // 2 x 16 KB kt-chunks

  const int tid  = threadIdx.x;
  const int wid  = tid >> 6;
  const int lane = tid & 63;
  const int lr   = lane & 15;   // X row within the wave's 16-row tile
  const int lg   = lane >> 4;   // k-chunk group; D reg-quad selects output cols

  const long row0 = (long)blockIdx.x * 64 + wid * 16;   // wave's 16 rows
  long r0 = row0 + lr;
  const float* p0 = X + (r0 < nrows ? r0 : 0) * 128 + lg * 8;  // clamp: safe read

  // ---- prologue: stage W chunk 0 (16 KB = 1024 float4); X for kt=0,1 ----
  {
    const float4* s_ = (const float4*)(WpkB);
    float4* d_ = (float4*)Wlds[0];
    d_[tid]       = s_[tid];
    d_[256 + tid] = s_[256 + tid];
    d_[512 + tid] = s_[512 + tid];
    d_[768 + tid] = s_[768 + tid];
  }
  float4 xa = *(const float4*)(p0);
  float4 xb = *(const float4*)(p0 + 4);
  float4 na = *(const float4*)(p0 + 32);
  float4 nb = *(const float4*)(p0 + 36);

  __syncthreads();

  f32x4 acc[8] = {};

#define CVT1(dsth, dstl, idx, val)                                   \
  { float v_ = (val); _Float16 h_ = (_Float16)v_;                    \
    dsth[idx] = h_; dstl[idx] = (_Float16)(v_ - (float)h_); }
#define CVT8(dsth, dstl, v0, v1)                                     \
  CVT1(dsth, dstl, 0, (v0).x) CVT1(dsth, dstl, 1, (v0).y)            \
  CVT1(dsth, dstl, 2, (v0).z) CVT1(dsth, dstl, 3, (v0).w)            \
  CVT1(dsth, dstl, 4, (v1).x) CVT1(dsth, dstl, 5, (v1).y)            \
  CVT1(dsth, dstl, 6, (v1).z) CVT1(dsth, dstl, 7, (v1).w)

#define MFMA(a, b, c) __builtin_amdgcn_mfma_f32_16x16x32_f16((a), (b), (c), 0, 0, 0)

// HASN1: chunk kt+1 exists (stage W, shift X); HASN2: kt+2 exists (load X)
#define KT_STEP(kt, HASN1, HASN2)                                        \
  {                                                                      \
    float4 sw0, sw1, sw2, sw3;                                           \
    if (HASN1) {                                                         \
      const float4* s_ = (const float4*)(WpkB + ((kt) + 1) * 8192);      \
      sw0 = s_[tid];                                                     \
      sw1 = s_[256 + tid];                                               \
      sw2 = s_[512 + tid];                                               \
      sw3 = s_[768 + tid];                                               \
    }                                                                    \
    half8 xh, xl;                                                        \
    CVT8(xh, xl, xa, xb);                                                \
    if (HASN1) { xa = na; xb = nb; }                                     \
    if (HASN2) {                                                         \
      na = *(const float4*)(p0 + ((kt) + 2) * 32);                       \
      nb = *(const float4*)(p0 + ((kt) + 2) * 32 + 4);                   \
    }                                                                    \
    _Pragma("unroll")                                                    \
    for (int nt = 0; nt < 8; ++nt) {                                     \
      const _Float16* f = &Wlds[(kt) & 1][nt * 1024 + lane * 8];         \
      half8 wh = *(const half8*)(f);                                     \
      half8 wl = *(const half8*)(f + 512);                               \
      acc[nt] = MFMA(wh, xh, acc[nt]);                                   \
      acc[nt] = MFMA(wh, xl, acc[nt]);                                   \
      acc[nt] = MFMA(wl, xh, acc[nt]);                                   \
    }                                                                    \
    if (HASN1) {                                                         \
      float4* d_ = (float4*)Wlds[((kt) + 1) & 1];                        \
      d_[tid]       = sw0;                                               \
      d_[256 + tid] = sw1;                                               \
      d_[512 + tid] = sw2;                                               \
      d_[768 + tid] = sw3;                                               \
      __syncthreads();                                                   \
    }                                                                    \
  }

  KT_STEP(0, 1, 1)
  KT_STEP(1, 1, 1)
  KT_STEP(2, 1, 0)
  KT_STEP(3, 0, 0)

#undef KT_STEP
#undef MFMA
#undef CVT8
#undef CVT1

  // ---- epilogue: D layout (swapped operands): lane -> row = row0 + lr,
  //      cols = nt*16 + lg*4 + (0..3) -> packed 8B stores ----
  long row = row0 + lr;
  if (row < nrows) {
    __half* yr = Y + row * 128;
    #pragma unroll
    for (int nt = 0; nt < 8; ++nt) {
      float4 bv = make_float4(0.f, 0.f, 0.f, 0.f);
      if (which) bv = *(const float4*)(bias + nt * 16 + lg * 4);
      __half2 v01 = __floats2half2_rn(acc[nt][0] + bv.x, acc[nt][1] + bv.y);
      __half2 v23 = __floats2half2_rn(acc[nt][2] + bv.z, acc[nt][3] + bv.w);
      uint2 u;
      u.x = *(unsigned int*)&v01;
      u.y = *(unsigned int*)&v23;
      *(uint2*)(yr + nt * 16 + lg * 4) = u;
    }
  }
}

// One block per segment. (FROZEN since R7 — at a pattern-BW wall: 72-76 us /
// 3.3-3.4 TB/s beyond-L2 invariant across 4 structures; traffic irreducible
// in fp16 and fp8 fails the error budget)
__global__ __launch_bounds__(256) void seg_softmax(
    const __half* __restrict__ xjp, const __half* __restrict__ xip,
    const int* __restrict__ ei, const int* __restrict__ segs,
    const float* __restrict__ mlpW, const float* __restrict__ prelu_w,
    const float* __restrict__ mlp_b, float* __restrict__ out, int E) {
  const int start = segs[blockIdx.x];
  const int end = segs[blockIdx.x + 1];
  const int cnt = end - start;
  if (cnt <= 0) return;

  __shared__ float aS[CAP];
  __shared__ float red[8];

  const int tid = threadIdx.x;
  const int lane = tid & 63;
  const int wid = tid >> 6;
  const int g   = tid >> 4;          // 16 quarter-wave groups per block
  const int ql  = tid & 15;          // lane within group: 8 features x fp16

  const float4 w0 = *(const float4*)(mlpW + ql * 8);
  const float4 w1 = *(const float4*)(mlpW + ql * 8 + 4);
  const float pw = prelu_w[0];
  const float mb = mlp_b[0];
  const bool useLds = (cnt <= CAP);

  const uint4* XJ = (const uint4*)xjp;   // one row = 16 uint4 (256 B)
  const uint4* XI = (const uint4*)xip;
  const h2v pwv = { (_Float16)pw, (_Float16)pw };
  const h2v zv  = { (_Float16)0.f, (_Float16)0.f };

  // ---- phase 1: alpha (4 consecutive edges per group per iteration) ----
  for (int e0 = start + g * 4; e0 < end; e0 += 64) {
    const int eB = e0 + 1, eC = e0 + 2, eD = e0 + 3;
    const bool vB = (eB < end), vC = (eC < end), vD = (eD < end);
    int sA = ei[e0],            dA = ei[E + e0];
    int sB = vB ? ei[eB] : sA,  dB = vB ? ei[E + eB] : dA;
    int sC = vC ? ei[eC] : sA,  dC = vC ? ei[E + eC] : dA;
    int sD = vD ? ei[eD] : sA,  dD = vD ? ei[E + eD] : dA;

    uint4 aA = XJ[(size_t)sA * 16 + ql], bA = XI[(size_t)dA * 16 + ql];
    uint4 aB = XJ[(size_t)sB * 16 + ql], bB = XI[(size_t)dB * 16 + ql];
    uint4 aC = XJ[(size_t)sC * 16 + ql], bC = XI[(size_t)dC * 16 + ql];
    uint4 aD = XJ[(size_t)sD * 16 + ql], bD = XI[(size_t)dD * 16 + ql];

    float pA, pB, pC, pD;
#define EALPHA(av, bv, p)                                                   \
    {                                                                       \
      h2v h0 = *(h2v*)&(av).x + *(h2v*)&(bv).x;                             \
      h2v h1 = *(h2v*)&(av).y + *(h2v*)&(bv).y;                             \
      h2v h2 = *(h2v*)&(av).z + *(h2v*)&(bv).z;                             \
      h2v h3 = *(h2v*)&(av).w + *(h2v*)&(bv).w;                             \
      h0 = __builtin_elementwise_max(h0, zv)                                \
         + pwv * __builtin_elementwise_min(h0, zv);                         \
      h1 = __builtin_elementwise_max(h1, zv)                                \
         + pwv * __builtin_elementwise_min(h1, zv);                         \
      h2 = __builtin_elementwise_max(h2, zv)                                \
         + pwv * __builtin_elementwise_min(h2, zv);                         \
      h3 = __builtin_elementwise_max(h3, zv)                                \
         + pwv * __builtin_elementwise_min(h3, zv);                         \
      p = (float)h0.x * w0.x;                                               \
      p = fmaf((float)h0.y, w0.y, p); p = fmaf((float)h1.x, w0.z, p);       \
      p = fmaf((float)h1.y, w0.w, p); p = fmaf((float)h2.x, w1.x, p);       \
      p = fmaf((float)h2.y, w1.y, p); p = fmaf((float)h3.x, w1.z, p);       \
      p = fmaf((float)h3.y, w1.w, p);                                       \
    }
    EALPHA(aA, bA, pA);
    EALPHA(aB, bB, pB);
    EALPHA(aC, bC, pC);
    EALPHA(aD, bD, pD);
#undef EALPHA

    #pragma unroll
    for (int off = 1; off < 16; off <<= 1) {
      pA += __shfl_xor(pA, off, 64);
      pB += __shfl_xor(pB, off, 64);
      pC += __shfl_xor(pC, off, 64);
      pD += __shfl_xor(pD, off, 64);
    }
    if (ql == 0) {
      if (useLds) {
        aS[e0 - start] = pA + mb;
        if (vB) aS[eB - start] = pB + mb;
        if (vC) aS[eC - start] = pC + mb;
        if (vD) aS[eD - start] = pD + mb;
      } else {
        out[e0] = pA + mb;
        if (vB) out[eB] = pB + mb;
        if (vC) out[eC] = pC + mb;
        if (vD) out[eD] = pD + mb;
      }
    }
  }
  __syncthreads();

  // ---- phase 2: block max ----
  float m = -FLT_MAX;
  if (useLds) { for (int i = tid; i < cnt; i += 256) m = fmaxf(m, aS[i]); }
  else        { for (int i = tid; i < cnt; i += 256) m = fmaxf(m, out[start + i]); }
  #pragma unroll
  for (int off = 1; off < 64; off <<= 1) m = fmaxf(m, __shfl_xor(m, off, 64));
  if (lane == 0) red[wid] = m;
  __syncthreads();
  m = fmaxf(fmaxf(red[0], red[1]), fmaxf(red[2], red[3]));

  // ---- phase 3: exp + block sum ----
  float s = 0.f;
  if (useLds) {
    for (int i = tid; i < cnt; i += 256) { float x = expf(aS[i] - m); aS[i] = x; s += x; }
  } else {
    for (int i = tid; i < cnt; i += 256) { float x = expf(out[start + i] - m); out[start + i] = x; s += x; }
  }
  #pragma unroll
  for (int off = 1; off < 64; off <<= 1) s += __shfl_xor(s, off, 64);
  if (lane == 0) red[4 + wid] = s;
  __syncthreads();
  s = (red[4] + red[5]) + (red[6] + red[7]);

  // ---- phase 4: normalize + write ----
  const float inv = 1.0f / (s + 1e-16f);
  if (useLds) { for (int i = tid; i < cnt; i += 256) out[start + i] = aS[i] * inv; }
  else        { for (int i = tid; i < cnt; i += 256) out[start + i] *= inv; }
}

extern "C" void kernel_launch(void* const* d_in, const int* in_sizes, int n_in,
                              void* d_out, int out_size, void* d_ws, size_t ws_size,
                              hipStream_t stream) {
  const float* x_j      = (const float*)d_in[0];
  const float* x_i      = (const float*)d_in[1];
  const int*   edge_idx = (const int*)d_in[2];
  const int*   batch    = (const int*)d_in[3];
  const float* w_j      = (const float*)d_in[4];
  const float* w_i      = (const float*)d_in[5];
  const float* bias     = (const float*)d_in[6];
  const float* prelu_w  = (const float*)d_in[7];
  const float* mlp_W    = (const float*)d_in[8];
  const float* mlp_b    = (const float*)d_in[9];
  const int nnodes = in_sizes[0] / 128;
  const int E = in_sizes[3];

  __half* Wpk = (__half*)d_ws;                    // 65536 halves = 128 KB
  __half* xjp = Wpk + 65536;
  __half* xip = xjp + (size_t)nnodes * 128;
  int* segs   = (int*)(xip + (size_t)nnodes * 128);

  hipLaunchKernelGGL(setup, dim3(49), dim3(256), 0, stream,
                     batch, segs, E, w_j, w_i, Wpk);

  int gblocks = (nnodes + 63) / 64;
  hipLaunchKernelGGL(proj_mfma, dim3(gblocks, 2), dim3(256), 0, stream,
                     x_j, x_i, bias, Wpk, xjp, xip, nnodes);

  hipLaunchKernelGGL(seg_softmax, dim3(NSEG), dim3(256), 0, stream,
                     xjp, xip, edge_idx, segs, mlp_W, prelu_w, mlp_b,
                     (float*)d_out, E);
}

// Round 11
// 238.688 us; speedup vs baseline: 1.3472x; 1.0263x over previous
//
#include <hip/hip_runtime.h>
#include <hip/hip_fp16.h>
#include <float.h>

#define NSEG 4096
#define CAP 2048   // max edges/segment held in LDS (max segment count ~330)

typedef __attribute__((ext_vector_type(8))) _Float16 half8;
typedef __attribute__((ext_vector_type(2))) _Float16 h2v;
typedef __attribute__((ext_vector_type(4))) float f32x4;
typedef __attribute__((address_space(1))) const unsigned int guint;
typedef __attribute__((address_space(3))) unsigned int luint;

// ---- fused setup: seg_bounds (blocks 0..16) + pack_w (blocks 17..48) ----
__global__ __launch_bounds__(256) void setup(
    const int* __restrict__ batch, int* __restrict__ segs, int E,
    const float* __restrict__ Wj, const float* __restrict__ Wi,
    __half* __restrict__ Wpk) {
  const int bid = blockIdx.x;
  if (bid < 17) {
    // segment boundaries: segs[b] = first edge index with batch >= b
    int b = bid * 256 + threadIdx.x;
    if (b > NSEG) return;
    int lo = 0, hi = E;
    while (lo < hi) { int mid = (lo + hi) >> 1; if (batch[mid] < b) lo = mid + 1; else hi = mid; }
    segs[b] = lo;
  } else {
    // pack W_j / W_i into MFMA fragment order, split fp16 hi/lo.
    // Layout (halves): Wpk[which][kt*8+nt][h(0=hi,1=lo)][lane][r]
    //   value = W[k][n], k = kt*32 + (l>>4)*8 + r, n = nt*16 + (l&15)
    int tid = (bid - 17) * 256 + threadIdx.x;
    for (int idx = tid; idx < 2 * 4 * 8 * 64 * 8; idx += 32 * 256) {
      int r     = idx & 7;
      int l     = (idx >> 3) & 63;
      int nt    = (idx >> 9) & 7;
      int kt    = (idx >> 12) & 3;
      int which = idx >> 14;
      const float* W = which ? Wi : Wj;
      int k = kt * 32 + (l >> 4) * 8 + r;
      int n = nt * 16 + (l & 15);
      float v = W[k * 128 + n];
      __half hi = __float2half(v);                         // RNE
      __half lo = __float2half(v - __half2float(hi));      // exact residual
      size_t base = ((size_t)which * 32 + (size_t)(kt * 8 + nt)) * 1024;
      Wpk[base + l * 8 + r]       = hi;
      Wpk[base + 512 + l * 8 + r] = lo;
    }
  }
}

// ---- projection GEMM on matrix cores: Y = fp16(X @ W (+bias for which==1)) ----
// v6 (attack proj's ~60us vs ~24us floor = staging-latency exposure):
//  - W staged via __builtin_amdgcn_global_load_lds width=16 (linear dest =
//    wave-uniform base + lane*16 — exactly our pattern): no VGPR round-trip,
//    no ds_write tail; loads issued at TOP of kt-step, only wait is the
//    barrier's vmcnt drain AFTER the 24-MFMA cluster
//  - full-row X upfront: 8 independent float4/lane issued in the prologue,
//    drained by the staging barrier -> zero mid-loop X stalls
//  - 64-row dispatch-ordered blocks (R9 proved dispatch-order locality is
//    essential); 32 KB LDS double-buffer; __launch_bounds__(256,4)
//  - accumulation order per output unchanged -> bitwise-identical Y
__global__ __launch_bounds__(256, 4) void proj_mfma(
    const float* __restrict__ Xj, const float* __restrict__ Xi,
    const float* __restrict__ bias, const __half* __restrict__ Wpk,
    __half* __restrict__ Yj, __half* __restrict__ Yi, int nrows) {
  const int which = blockIdx.y;
  const float* X = which ? Xi : Xj;
  __half* Y = which ? Yi : Yj;
  const _Float16* WpkB = (const _Float16*)Wpk + (size_t)which * 32768;

  __shared__ _Float16 Wlds[2][8192];   // 2 x 16 KB kt-chunks

  const int tid  = threadIdx.x;
  const int wid  = tid >> 6;
  const int lane = tid & 63;
  const int lr   = lane & 15;   // X row within the wave's 16-row tile
  const int lg   = lane >> 4;   // k-chunk group; D reg-quad selects output cols

  const long row0 = (long)blockIdx.x * 64 + wid * 16;   // wave's 16 rows
  long r0 = row0 + lr;
  const float* p0 = X + (r0 < nrows ? r0 : 0) * 128 + lg * 8;  // clamp: safe read

// stage one 16 KB W chunk into Wlds[buf] via global_load_lds (4 lines/thread;
// per-wave uniform LDS base + lane*16B matches the HW linear-dest semantics)
#define STAGE_CHUNK(buf, chunkIdx)                                            \
  {                                                                           \
    const float4* s_ = (const float4*)(WpkB + (chunkIdx) * 8192);             \
    _Float16* lb_ = (_Float16*)Wlds[buf];                                     \
    _Pragma("unroll")                                                         \
    for (int it_ = 0; it_ < 4; ++it_) {                                       \
      __builtin_amdgcn_global_load_lds(                                       \
          (guint*)(const void*)(s_ + it_ * 256 + tid),                        \
          (luint*)(void*)(lb_ + (it_ * 256 + wid * 64) * 8),                  \
          16, 0, 0);                                                          \
    }                                                                         \
  }

  // ---- prologue: stage W chunk 0 + ALL X (8 independent float4/lane) ----
  STAGE_CHUNK(0, 0)
  float4 xr[8];
  #pragma unroll
  for (int kt = 0; kt < 4; ++kt) {
    xr[2 * kt]     = *(const float4*)(p0 + kt * 32);
    xr[2 * kt + 1] = *(const float4*)(p0 + kt * 32 + 4);
  }

  __syncthreads();   // drains vmcnt: chunk0 in LDS, X rows in regs

  f32x4 acc[8] = {};

#define CVT1(dsth, dstl, idx, val)                                   \
  { float v_ = (val); _Float16 h_ = (_Float16)v_;                    \
    dsth[idx] = h_; dstl[idx] = (_Float16)(v_ - (float)h_); }
#define CVT8(dsth, dstl, v0, v1)                                     \
  CVT1(dsth, dstl, 0, (v0).x) CVT1(dsth, dstl, 1, (v0).y)            \
  CVT1(dsth, dstl, 2, (v0).z) CVT1(dsth, dstl, 3, (v0).w)            \
  CVT1(dsth, dstl, 4, (v1).x) CVT1(dsth, dstl, 5, (v1).y)            \
  CVT1(dsth, dstl, 6, (v1).z) CVT1(dsth, dstl, 7, (v1).w)

#define MFMA(a, b, c) __builtin_amdgcn_mfma_f32_16x16x32_f16((a), (b), (c), 0, 0, 0)

// HASN1: chunk kt+1 exists -> stage it at top (latency hidden under MFMAs),
// barrier at end publishes it
#define KT_STEP(kt, HASN1)                                               \
  {                                                                      \
    if (HASN1) STAGE_CHUNK(((kt) + 1) & 1, (kt) + 1)                     \
    half8 xh, xl;                                                        \
    CVT8(xh, xl, xr[2 * (kt)], xr[2 * (kt) + 1]);                        \
    _Pragma("unroll")                                                    \
    for (int nt = 0; nt < 8; ++nt) {                                     \
      const _Float16* f = &Wlds[(kt) & 1][nt * 1024 + lane * 8];         \
      half8 wh = *(const half8*)(f);                                     \
      half8 wl = *(const half8*)(f + 512);                               \
      acc[nt] = MFMA(wh, xh, acc[nt]);                                   \
      acc[nt] = MFMA(wh, xl, acc[nt]);                                   \
      acc[nt] = MFMA(wl, xh, acc[nt]);                                   \
    }                                                                    \
    if (HASN1) __syncthreads();                                          \
  }

  KT_STEP(0, 1)
  KT_STEP(1, 1)
  KT_STEP(2, 1)
  KT_STEP(3, 0)

#undef KT_STEP
#undef MFMA
#undef CVT8
#undef CVT1
#undef STAGE_CHUNK

  // ---- epilogue: D layout (swapped operands): lane -> row = row0 + lr,
  //      cols = nt*16 + lg*4 + (0..3) -> packed 8B stores ----
  long row = row0 + lr;
  if (row < nrows) {
    __half* yr = Y + row * 128;
    #pragma unroll
    for (int nt = 0; nt < 8; ++nt) {
      float4 bv = make_float4(0.f, 0.f, 0.f, 0.f);
      if (which) bv = *(const float4*)(bias + nt * 16 + lg * 4);
      __half2 v01 = __floats2half2_rn(acc[nt][0] + bv.x, acc[nt][1] + bv.y);
      __half2 v23 = __floats2half2_rn(acc[nt][2] + bv.z, acc[nt][3] + bv.w);
      uint2 u;
      u.x = *(unsigned int*)&v01;
      u.y = *(unsigned int*)&v23;
      *(uint2*)(yr + nt * 16 + lg * 4) = u;
    }
  }
}

// One block per segment. (FROZEN since R7 — at a pattern-BW wall: 72-76 us /
// 3.3-3.4 TB/s beyond-L2 invariant across 4 structures; traffic irreducible
// in fp16 and fp8 fails the error budget)
__global__ __launch_bounds__(256) void seg_softmax(
    const __half* __restrict__ xjp, const __half* __restrict__ xip,
    const int* __restrict__ ei, const int* __restrict__ segs,
    const float* __restrict__ mlpW, const float* __restrict__ prelu_w,
    const float* __restrict__ mlp_b, float* __restrict__ out, int E) {
  const int start = segs[blockIdx.x];
  const int end = segs[blockIdx.x + 1];
  const int cnt = end - start;
  if (cnt <= 0) return;

  __shared__ float aS[CAP];
  __shared__ float red[8];

  const int tid = threadIdx.x;
  const int lane = tid & 63;
  const int wid = tid >> 6;
  const int g   = tid >> 4;          // 16 quarter-wave groups per block
  const int ql  = tid & 15;          // lane within group: 8 features x fp16

  const float4 w0 = *(const float4*)(mlpW + ql * 8);
  const float4 w1 = *(const float4*)(mlpW + ql * 8 + 4);
  const float pw = prelu_w[0];
  const float mb = mlp_b[0];
  const bool useLds = (cnt <= CAP);

  const uint4* XJ = (const uint4*)xjp;   // one row = 16 uint4 (256 B)
  const uint4* XI = (const uint4*)xip;
  const h2v pwv = { (_Float16)pw, (_Float16)pw };
  const h2v zv  = { (_Float16)0.f, (_Float16)0.f };

  // ---- phase 1: alpha (4 consecutive edges per group per iteration) ----
  for (int e0 = start + g * 4; e0 < end; e0 += 64) {
    const int eB = e0 + 1, eC = e0 + 2, eD = e0 + 3;
    const bool vB = (eB < end), vC = (eC < end), vD = (eD < end);
    int sA = ei[e0],            dA = ei[E + e0];
    int sB = vB ? ei[eB] : sA,  dB = vB ? ei[E + eB] : dA;
    int sC = vC ? ei[eC] : sA,  dC = vC ? ei[E + eC] : dA;
    int sD = vD ? ei[eD] : sA,  dD = vD ? ei[E + eD] : dA;

    uint4 aA = XJ[(size_t)sA * 16 + ql], bA = XI[(size_t)dA * 16 + ql];
    uint4 aB = XJ[(size_t)sB * 16 + ql], bB = XI[(size_t)dB * 16 + ql];
    uint4 aC = XJ[(size_t)sC * 16 + ql], bC = XI[(size_t)dC * 16 + ql];
    uint4 aD = XJ[(size_t)sD * 16 + ql], bD = XI[(size_t)dD * 16 + ql];

    float pA, pB, pC, pD;
#define EALPHA(av, bv, p)                                                   \
    {                                                                       \
      h2v h0 = *(h2v*)&(av).x + *(h2v*)&(bv).x;                             \
      h2v h1 = *(h2v*)&(av).y + *(h2v*)&(bv).y;                             \
      h2v h2 = *(h2v*)&(av).z + *(h2v*)&(bv).z;                             \
      h2v h3 = *(h2v*)&(av).w + *(h2v*)&(bv).w;                             \
      h0 = __builtin_elementwise_max(h0, zv)                                \
         + pwv * __builtin_elementwise_min(h0, zv);                         \
      h1 = __builtin_elementwise_max(h1, zv)                                \
         + pwv * __builtin_elementwise_min(h1, zv);                         \
      h2 = __builtin_elementwise_max(h2, zv)                                \
         + pwv * __builtin_elementwise_min(h2, zv);                         \
      h3 = __builtin_elementwise_max(h3, zv)                                \
         + pwv * __builtin_elementwise_min(h3, zv);                         \
      p = (float)h0.x * w0.x;                                               \
      p = fmaf((float)h0.y, w0.y, p); p = fmaf((float)h1.x, w0.z, p);       \
      p = fmaf((float)h1.y, w0.w, p); p = fmaf((float)h2.x, w1.x, p);       \
      p = fmaf((float)h2.y, w1.y, p); p = fmaf((float)h3.x, w1.z, p);       \
      p = fmaf((float)h3.y, w1.w, p);                                       \
    }
    EALPHA(aA, bA, pA);
    EALPHA(aB, bB, pB);
    EALPHA(aC, bC, pC);
    EALPHA(aD, bD, pD);
#undef EALPHA

    #pragma unroll
    for (int off = 1; off < 16; off <<= 1) {
      pA += __shfl_xor(pA, off, 64);
      pB += __shfl_xor(pB, off, 64);
      pC += __shfl_xor(pC, off, 64);
      pD += __shfl_xor(pD, off, 64);
    }
    if (ql == 0) {
      if (useLds) {
        aS[e0 - start] = pA + mb;
        if (vB) aS[eB - start] = pB + mb;
        if (vC) aS[eC - start] = pC + mb;
        if (vD) aS[eD - start] = pD + mb;
      } else {
        out[e0] = pA + mb;
        if (vB) out[eB] = pB + mb;
        if (vC) out[eC] = pC + mb;
        if (vD) out[eD] = pD + mb;
      }
    }
  }
  __syncthreads();

  // ---- phase 2: block max ----
  float m = -FLT_MAX;
  if (useLds) { for (int i = tid; i < cnt; i += 256) m = fmaxf(m, aS[i]); }
  else        { for (int i = tid; i < cnt; i += 256) m = fmaxf(m, out[start + i]); }
  #pragma unroll
  for (int off = 1; off < 64; off <<= 1) m = fmaxf(m, __shfl_xor(m, off, 64));
  if (lane == 0) red[wid] = m;
  __syncthreads();
  m = fmaxf(fmaxf(red[0], red[1]), fmaxf(red[2], red[3]));

  // ---- phase 3: exp + block sum ----
  float s = 0.f;
  if (useLds) {
    for (int i = tid; i < cnt; i += 256) { float x = expf(aS[i] - m); aS[i] = x; s += x; }
  } else {
    for (int i = tid; i < cnt; i += 256) { float x = expf(out[start + i] - m); out[start + i] = x; s += x; }
  }
  #pragma unroll
  for (int off = 1; off < 64; off <<= 1) s += __shfl_xor(s, off, 64);
  if (lane == 0) red[4 + wid] = s;
  __syncthreads();
  s = (red[4] + red[5]) + (red[6] + red[7]);

  // ---- phase 4: normalize + write ----
  const float inv = 1.0f / (s + 1e-16f);
  if (useLds) { for (int i = tid; i < cnt; i += 256) out[start + i] = aS[i] * inv; }
  else        { for (int i = tid; i < cnt; i += 256) out[start + i] *= inv; }
}

extern "C" void kernel_launch(void* const* d_in, const int* in_sizes, int n_in,
                              void* d_out, int out_size, void* d_ws, size_t ws_size,
                              hipStream_t stream) {
  const float* x_j      = (const float*)d_in[0];
  const float* x_i      = (const float*)d_in[1];
  const int*   edge_idx = (const int*)d_in[2];
  const int*   batch    = (const int*)d_in[3];
  const float* w_j      = (const float*)d_in[4];
  const float* w_i      = (const float*)d_in[5];
  const float* bias     = (const float*)d_in[6];
  const float* prelu_w  = (const float*)d_in[7];
  const float* mlp_W    = (const float*)d_in[8];
  const float* mlp_b    = (const float*)d_in[9];
  const int nnodes = in_sizes[0] / 128;
  const int E = in_sizes[3];

  __half* Wpk = (__half*)d_ws;                    // 65536 halves = 128 KB
  __half* xjp = Wpk + 65536;
  __half* xip = xjp + (size_t)nnodes * 128;
  int* segs   = (int*)(xip + (size_t)nnodes * 128);

  hipLaunchKernelGGL(setup, dim3(49), dim3(256), 0, stream,
                     batch, segs, E, w_j, w_i, Wpk);

  int gblocks = (nnodes + 63) / 64;
  hipLaunchKernelGGL(proj_mfma, dim3(gblocks, 2), dim3(256), 0, stream,
                     x_j, x_i, bias, Wpk, xjp, xip, nnodes);

  hipLaunchKernelGGL(seg_softmax, dim3(NSEG), dim3(256), 0, stream,
                     xjp, xip, edge_idx, segs, mlp_W, prelu_w, mlp_b,
                     (float*)d_out, E);
}